// Round 6
// baseline (611.677 us; speedup 1.0000x reference)
//
#include <hip/hip_runtime.h>

typedef unsigned short u16;
typedef unsigned int u32;
typedef unsigned long long u64;
typedef __attribute__((ext_vector_type(8))) short bf16x8;
typedef __attribute__((ext_vector_type(4))) float f32x4;

#define NB 2
#define NS 2048
#define NDM 1024
#define NH 16

__device__ __forceinline__ u16 f2bf(float f) {
  union { float f; unsigned u; } v; v.f = f;
  return (u16)((v.u + 0x7fffu + ((v.u >> 16) & 1u)) >> 16);
}

__global__ __launch_bounds__(256) void cast_bf16(const float* __restrict__ in,
                                                 u16* __restrict__ out, int n4) {
  int i = blockIdx.x * 256 + threadIdx.x;
  if (i < n4) {
    const float4 v = reinterpret_cast<const float4*>(in)[i];
    ushort4 o; o.x = f2bf(v.x); o.y = f2bf(v.y); o.z = f2bf(v.z); o.w = f2bf(v.w);
    reinterpret_cast<ushort4*>(out)[i] = o;
  }
}

// in: f32 [1024][1024] row-major -> out: bf16 [1024][1024] = in^T
__global__ __launch_bounds__(256) void transpose_w(const float* __restrict__ in,
                                                   u16* __restrict__ out) {
  __shared__ float tile[32][33];
  int bx = blockIdx.x, by = blockIdx.y;
  int x = threadIdx.x & 31, y0 = threadIdx.x >> 5;
#pragma unroll
  for (int i = 0; i < 4; i++) {
    int y = y0 + i * 8;
    tile[y][x] = in[(by * 32 + y) * NDM + bx * 32 + x];
  }
  __syncthreads();
#pragma unroll
  for (int i = 0; i < 4; i++) {
    int y = y0 + i * 8;
    out[(bx * 32 + y) * NDM + by * 32 + x] = f2bf(tile[x][y]);
  }
}

// ---- mask [B,S,S] -> bitmask, 1 bit/col ----
__global__ __launch_bounds__(256) void mask2bits(const u32* __restrict__ mask, u32* __restrict__ mb) {
  int idx = blockIdx.x * 256 + threadIdx.x;
  u32 mw0 = mask[threadIdx.x & 63];
  bool floatmode = (__ballot(mw0 == 0x3F800000u) != 0ull);
  bool bytemode = !floatmode && (__ballot((mw0 >> 8) != 0u) != 0ull);
  int row = idx >> 6;
  int wword = idx & 63;
  u32 bits = 0;
  if (!bytemode) {
    const uint4* p = reinterpret_cast<const uint4*>(mask + (size_t)row * 2048 + wword * 32);
#pragma unroll
    for (int i = 0; i < 8; i++) {
      uint4 v = p[i];
      bits |= (v.x ? 1u : 0u) << (i * 4 + 0);
      bits |= (v.y ? 1u : 0u) << (i * 4 + 1);
      bits |= (v.z ? 1u : 0u) << (i * 4 + 2);
      bits |= (v.w ? 1u : 0u) << (i * 4 + 3);
    }
  } else {
    const uint4* p = reinterpret_cast<const uint4*>(
        reinterpret_cast<const unsigned char*>(mask) + (size_t)row * 2048 + wword * 32);
#pragma unroll
    for (int i = 0; i < 2; i++) {
      uint4 v = p[i];
      u32 wsv[4] = {v.x, v.y, v.z, v.w};
#pragma unroll
      for (int j = 0; j < 4; j++)
#pragma unroll
        for (int kq = 0; kq < 4; kq++)
          bits |= ((((wsv[j] >> (kq * 8)) & 0xffu) != 0u) ? 1u : 0u) << (i * 16 + j * 4 + kq);
    }
  }
  mb[idx] = bits;
}

// ---- 128x128-tile bf16 GEMM, B^T layout ----
struct GArgs { const u16* X; const u16* W; const float* bias; void* out; int mode; float scale; };

__global__ __launch_bounds__(256, 2) void gemm_bt(GArgs g0, GArgs g1, GArgs g2) {
  GArgs ga = (blockIdx.z == 0) ? g0 : (blockIdx.z == 1 ? g1 : g2);
  const int K = 1024, N = 1024;
  __shared__ u16 As[128 * 32];
  __shared__ u16 Bs[128 * 32];
  const int t = threadIdx.x, w = t >> 6, l = t & 63;
  const int m0 = blockIdx.x * 128, n0 = blockIdx.y * 128;
  const int wm = (w >> 1) * 64, wn = (w & 1) * 64;
  const f32x4 fz = {0.f, 0.f, 0.f, 0.f};
  f32x4 acc[4][4];
#pragma unroll
  for (int i = 0; i < 4; i++)
#pragma unroll
    for (int j = 0; j < 4; j++) acc[i][j] = fz;

  for (int k0 = 0; k0 < K; k0 += 32) {
#pragma unroll
    for (int i = 0; i < 2; i++) {
      int idx = i * 256 + w * 64 + l;
      int r = idx >> 2, c = (idx & 3) * 8;
      __builtin_amdgcn_global_load_lds(
          reinterpret_cast<const unsigned*>(ga.X + (size_t)(m0 + r) * K + k0 + c),
          reinterpret_cast<unsigned*>(&As[(i * 256 + w * 64) * 8]), 16, 0, 0);
      __builtin_amdgcn_global_load_lds(
          reinterpret_cast<const unsigned*>(ga.W + (size_t)(n0 + r) * K + k0 + c),
          reinterpret_cast<unsigned*>(&Bs[(i * 256 + w * 64) * 8]), 16, 0, 0);
    }
    __syncthreads();
    bf16x8 af[4], bfr[4];
#pragma unroll
    for (int mt = 0; mt < 4; mt++)
      af[mt] = *reinterpret_cast<const bf16x8*>(&As[(wm + mt * 16 + (l & 15)) * 32 + (l >> 4) * 8]);
#pragma unroll
    for (int nt = 0; nt < 4; nt++)
      bfr[nt] = *reinterpret_cast<const bf16x8*>(&Bs[(wn + nt * 16 + (l & 15)) * 32 + (l >> 4) * 8]);
#pragma unroll
    for (int mt = 0; mt < 4; mt++)
#pragma unroll
      for (int nt = 0; nt < 4; nt++)
        acc[mt][nt] = __builtin_amdgcn_mfma_f32_16x16x32_bf16(af[mt], bfr[nt], acc[mt][nt], 0, 0, 0);
    __syncthreads();
  }

#pragma unroll
  for (int nt = 0; nt < 4; nt++) {
    int n = n0 + wn + nt * 16 + (l & 15);
    float bias = ga.bias[n];
#pragma unroll
    for (int mt = 0; mt < 4; mt++) {
      int mb = m0 + wm + mt * 16 + ((l >> 4) << 2);
#pragma unroll
      for (int r = 0; r < 4; r++) {
        int m = mb + r;
        float v = (acc[mt][nt][r] + bias) * ga.scale;
        if (ga.mode == 2) {
          reinterpret_cast<float*>(ga.out)[(size_t)m * N + n] = v;
        } else {
          int b = m >> 11, s = m & 2047, h = n >> 6, d = n & 63;
          if (ga.mode == 0)
            reinterpret_cast<u16*>(ga.out)[(((size_t)(b * NH + h) * NS + s) << 6) + d] = f2bf(v);
          else
            reinterpret_cast<u16*>(ga.out)[((size_t)(b * NH + h) * 64 + d) * NS + s] = f2bf(v);
        }
      }
    }
  }
}

// ---- attention: barrier-free 2-pass.
// Pass A: QK + exp + rowsum + UNNORMALIZED PV (scale folded in after reduce) -> ctx.
// Pass B: QK recompute + exp*rs -> full-line plain f32x4 attn stores (no V, no PV). ----
__global__ __launch_bounds__(256, 3) void attn_kernel(
    const u16* __restrict__ qh, const u16* __restrict__ kh, const u16* __restrict__ vT,
    const u64* __restrict__ mb64, float* __restrict__ attn, u16* __restrict__ ctx) {
  __shared__ u16 Ps[4][16 * 72];      // per-wave bf16 P tile (pass A: PV A-frag relayout)
  __shared__ float Pf[4][16 * 68];    // per-wave f32 P tile (pass B: full-line attn stores)
  const int t = threadIdx.x, w = t >> 6, l = t & 63;
  int id = blockIdx.x;
  int wgid = (id & 7) * 128 + (id >> 3);   // XCD-chunked bijective swizzle (1024 % 8 == 0)
  int qt = wgid & 31, pr = wgid >> 5;
  int h = pr & 15, b = pr >> 4;
  const size_t head = (size_t)b * NH + h;
  const u16* qp = qh + head * NS * 64;
  const u16* kp = kh + head * NS * 64;
  const u16* vp = vT + head * 64 * NS;
  const int qr0 = qt * 64 + w * 16;
  const int lo = l & 15, hi = l >> 4;
  const int rbase = hi << 2;
  const f32x4 fz = {0.f, 0.f, 0.f, 0.f};

  bf16x8 aq0, aq1;
  {
    const u16* p = qp + (size_t)(qr0 + lo) * 64 + hi * 8;
    aq0 = *reinterpret_cast<const bf16x8*>(p);
    aq1 = *reinterpret_cast<const bf16x8*>(p + 32);
  }
  const u64* mrow = mb64 + ((size_t)b * NS + qr0 + rbase) * 32;

  auto loadK = [&](bf16x8* dst, int c) {
    const u16* kb = kp + (size_t)(c * 64) * 64;
#pragma unroll
    for (int ct = 0; ct < 4; ++ct) {
      const u16* p = kb + (size_t)(ct * 16 + lo) * 64 + hi * 8;
      dst[2 * ct] = *reinterpret_cast<const bf16x8*>(p);
      dst[2 * ct + 1] = *reinterpret_cast<const bf16x8*>(p + 32);
    }
  };
  auto qk = [&](const bf16x8* bk, f32x4* s) {
#pragma unroll
    for (int ct = 0; ct < 4; ++ct) {
      f32x4 acc = fz;
      acc = __builtin_amdgcn_mfma_f32_16x16x32_bf16(aq0, bk[2 * ct], acc, 0, 0, 0);
      acc = __builtin_amdgcn_mfma_f32_16x16x32_bf16(aq1, bk[2 * ct + 1], acc, 0, 0, 0);
      s[ct] = acc;
    }
  };

  // ---- pass A: rowsum + unnormalized PV (q pre-scaled by 1/8 in projection) ----
  float rs[4] = {0.f, 0.f, 0.f, 0.f};
  f32x4 cacc[4];
#pragma unroll
  for (int i = 0; i < 4; i++) cacc[i] = fz;
  u16* psw = &Ps[w][0];

  {
    auto consumeA = [&](const bf16x8* bk, int cc) {
      u64 mwv[4] = {mrow[cc], mrow[32 + cc], mrow[64 + cc], mrow[96 + cc]};
      f32x4 s[4]; qk(bk, s);
      // V fragments issued early (latency hidden under exp + LDS relayout)
      bf16x8 bv[8];
      {
        const u16* vb = vp + cc * 64;
#pragma unroll
        for (int ct = 0; ct < 4; ++ct) {
          const u16* p = vb + (size_t)(ct * 16 + lo) * NS + hi * 8;
          bv[2 * ct] = *reinterpret_cast<const bf16x8*>(p);
          bv[2 * ct + 1] = *reinterpret_cast<const bf16x8*>(p + 32);
        }
      }
#pragma unroll
      for (int ct = 0; ct < 4; ++ct) {
        int bit = ct * 16 + lo;
#pragma unroll
        for (int r = 0; r < 4; ++r) {
          float p = ((mwv[r] >> bit) & 1ull) ? 0.f : __expf(s[ct][r]);
          rs[r] += p;
          psw[(rbase + r) * 72 + ct * 16 + lo] = f2bf(p);
        }
      }
      bf16x8 pa0 = *reinterpret_cast<const bf16x8*>(&psw[lo * 72 + hi * 8]);
      bf16x8 pa1 = *reinterpret_cast<const bf16x8*>(&psw[lo * 72 + 32 + hi * 8]);
#pragma unroll
      for (int ct = 0; ct < 4; ++ct) {
        cacc[ct] = __builtin_amdgcn_mfma_f32_16x16x32_bf16(pa0, bv[2 * ct], cacc[ct], 0, 0, 0);
        cacc[ct] = __builtin_amdgcn_mfma_f32_16x16x32_bf16(pa1, bv[2 * ct + 1], cacc[ct], 0, 0, 0);
      }
    };
    bf16x8 kA[8], kB[8];
    loadK(kA, 0);
    for (int c = 0; c < 32; c += 2) {
      loadK(kB, c + 1);
      consumeA(kA, c);
      if (c + 2 < 32) loadK(kA, c + 2);
      consumeA(kB, c + 1);
    }
  }
#pragma unroll
  for (int r = 0; r < 4; ++r) {
    float v = rs[r];
    v += __shfl_xor(v, 1); v += __shfl_xor(v, 2);
    v += __shfl_xor(v, 4); v += __shfl_xor(v, 8);
    rs[r] = 1.f / fmaxf(v, 1e-30f);
  }
  // scale PV by 1/rowsum and write ctx now: these stores drain under pass B
#pragma unroll
  for (int ct = 0; ct < 4; ++ct)
#pragma unroll
    for (int r = 0; r < 4; ++r) {
      int qr = qr0 + rbase + r;
      int dv = ct * 16 + lo;
      ctx[((size_t)b * NS + qr) * 1024 + h * 64 + dv] = f2bf(cacc[ct][r] * rs[r]);
    }

  // ---- pass B: recompute, normalized full-line attn stores (no V / PV) ----
  float* pfw = &Pf[w][0];
  float* abase = attn + (head * NS + qr0) * NS;
  {
    auto consumeB = [&](const bf16x8* bk, int cc) {
      u64 mwv[4] = {mrow[cc], mrow[32 + cc], mrow[64 + cc], mrow[96 + cc]};
      f32x4 s[4]; qk(bk, s);
#pragma unroll
      for (int ct = 0; ct < 4; ++ct) {
        int bit = ct * 16 + lo;
#pragma unroll
        for (int r = 0; r < 4; ++r) {
          float p = ((mwv[r] >> bit) & 1ull) ? 0.f : __expf(s[ct][r]) * rs[r];
          pfw[(rbase + r) * 68 + ct * 16 + lo] = p;
        }
      }
      // full-line (1KB/instr) plain stores — R2-proven clean write traffic
#pragma unroll
      for (int i2 = 0; i2 < 4; ++i2) {
        int row = i2 * 4 + hi;
        f32x4 pv4 = *reinterpret_cast<const f32x4*>(&pfw[row * 68 + lo * 4]);
        *reinterpret_cast<f32x4*>(abase + (size_t)row * NS + cc * 64 + lo * 4) = pv4;
      }
    };
    bf16x8 k0[8], k1[8], k2[8];
    loadK(k0, 0); loadK(k1, 1);
    for (int c = 0; c <= 27; c += 3) {           // modulo-3 rotated pipeline, 2 chunks ahead
      loadK(k2, c + 2); consumeB(k0, c);
      loadK(k0, c + 3); consumeB(k1, c + 1);
      loadK(k1, c + 4); consumeB(k2, c + 2);
    }
    consumeB(k0, 30); consumeB(k1, 31);
  }
}

extern "C" void kernel_launch(void* const* d_in, const int* in_sizes, int n_in,
                              void* d_out, int out_size, void* d_ws, size_t ws_size,
                              hipStream_t stream) {
  const float* Q = (const float*)d_in[0];
  const float* K = (const float*)d_in[1];
  const float* V = (const float*)d_in[2];
  const u32* mask = (const u32*)d_in[3];
  const float* wq = (const float*)d_in[4];
  const float* bq = (const float*)d_in[5];
  const float* wk = (const float*)d_in[6];
  const float* bk = (const float*)d_in[7];
  const float* wv = (const float*)d_in[8];
  const float* bv = (const float*)d_in[9];
  const float* wo = (const float*)d_in[10];
  const float* bo = (const float*)d_in[11];
  float* out = (float*)d_out;
  float* attn = out + (size_t)NB * NS * NDM;

  char* ws = (char*)d_ws;
  u16* Qb  = (u16*)(ws + 0);
  u16* Kb  = (u16*)(ws + 8388608);
  u16* Vb  = (u16*)(ws + 16777216);
  u16* wqT = (u16*)(ws + 25165824);
  u16* wkT = (u16*)(ws + 27262976);
  u16* wvT = (u16*)(ws + 29360128);
  u16* woT = (u16*)(ws + 31457280);
  u16* qhd = (u16*)(ws + 33554432);
  u16* khd = (u16*)(ws + 41943040);
  u16* vTd = (u16*)(ws + 50331648);
  u16* ctx = (u16*)(ws + 58720256);
  u32* mbits = (u32*)(ws + 0);

  cast_bf16<<<4096, 256, 0, stream>>>(Q, Qb, 1048576);
  cast_bf16<<<4096, 256, 0, stream>>>(K, Kb, 1048576);
  cast_bf16<<<4096, 256, 0, stream>>>(V, Vb, 1048576);
  transpose_w<<<dim3(32, 32), 256, 0, stream>>>(wq, wqT);
  transpose_w<<<dim3(32, 32), 256, 0, stream>>>(wk, wkT);
  transpose_w<<<dim3(32, 32), 256, 0, stream>>>(wv, wvT);
  transpose_w<<<dim3(32, 32), 256, 0, stream>>>(wo, woT);

  GArgs gq = {Qb, wqT, bq, (void*)qhd, 0, 0.125f};   // fold 1/sqrt(dk) into q
  GArgs gk = {Kb, wkT, bk, (void*)khd, 0, 1.0f};
  GArgs gv = {Vb, wvT, bv, (void*)vTd, 1, 1.0f};
  gemm_bt<<<dim3(32, 8, 3), 256, 0, stream>>>(gq, gk, gv);

  mask2bits<<<1024, 256, 0, stream>>>(mask, mbits);

  attn_kernel<<<1024, 256, 0, stream>>>(qhd, khd, vTd, (const u64*)mbits, attn, ctx);

  GArgs go = {ctx, woT, bo, d_out, 2, 1.0f};
  gemm_bt<<<dim3(32, 8, 1), 256, 0, stream>>>(go, go, go);
}

// Round 7
// 339.101 us; speedup vs baseline: 1.8038x; 1.8038x over previous
//
#include <hip/hip_runtime.h>

typedef unsigned short u16;
typedef unsigned int u32;
typedef unsigned long long u64;
typedef __attribute__((ext_vector_type(8))) short bf16x8;
typedef __attribute__((ext_vector_type(4))) float f32x4;

#define NB 2
#define NS 2048
#define NDM 1024
#define NH 16

#define MFMA_B16(a, b, c) __builtin_amdgcn_mfma_f32_16x16x32_bf16(a, b, c, 0, 0, 0)

__device__ __forceinline__ u16 f2bf(float f) {
  union { float f; unsigned u; } v; v.f = f;
  return (u16)((v.u + 0x7fffu + ((v.u >> 16) & 1u)) >> 16);
}

__global__ __launch_bounds__(256) void cast_bf16(const float* __restrict__ in,
                                                 u16* __restrict__ out, int n4) {
  int i = blockIdx.x * 256 + threadIdx.x;
  if (i < n4) {
    const float4 v = reinterpret_cast<const float4*>(in)[i];
    ushort4 o; o.x = f2bf(v.x); o.y = f2bf(v.y); o.z = f2bf(v.z); o.w = f2bf(v.w);
    reinterpret_cast<ushort4*>(out)[i] = o;
  }
}

// in: f32 [1024][1024] row-major -> out: bf16 [1024][1024] = in^T
__global__ __launch_bounds__(256) void transpose_w(const float* __restrict__ in,
                                                   u16* __restrict__ out) {
  __shared__ float tile[32][33];
  int bx = blockIdx.x, by = blockIdx.y;
  int x = threadIdx.x & 31, y0 = threadIdx.x >> 5;
#pragma unroll
  for (int i = 0; i < 4; i++) {
    int y = y0 + i * 8;
    tile[y][x] = in[(by * 32 + y) * NDM + bx * 32 + x];
  }
  __syncthreads();
#pragma unroll
  for (int i = 0; i < 4; i++) {
    int y = y0 + i * 8;
    out[(bx * 32 + y) * NDM + by * 32 + x] = f2bf(tile[x][y]);
  }
}

// ---- mask [B,S,S] -> bitmask, 1 bit/col (u32 word w covers cols w*32..w*32+31) ----
__global__ __launch_bounds__(256) void mask2bits(const u32* __restrict__ mask, u32* __restrict__ mb) {
  int idx = blockIdx.x * 256 + threadIdx.x;
  u32 mw0 = mask[threadIdx.x & 63];
  bool floatmode = (__ballot(mw0 == 0x3F800000u) != 0ull);
  bool bytemode = !floatmode && (__ballot((mw0 >> 8) != 0u) != 0ull);
  int row = idx >> 6;
  int wword = idx & 63;
  u32 bits = 0;
  if (!bytemode) {
    const uint4* p = reinterpret_cast<const uint4*>(mask + (size_t)row * 2048 + wword * 32);
#pragma unroll
    for (int i = 0; i < 8; i++) {
      uint4 v = p[i];
      bits |= (v.x ? 1u : 0u) << (i * 4 + 0);
      bits |= (v.y ? 1u : 0u) << (i * 4 + 1);
      bits |= (v.z ? 1u : 0u) << (i * 4 + 2);
      bits |= (v.w ? 1u : 0u) << (i * 4 + 3);
    }
  } else {
    const uint4* p = reinterpret_cast<const uint4*>(
        reinterpret_cast<const unsigned char*>(mask) + (size_t)row * 2048 + wword * 32);
#pragma unroll
    for (int i = 0; i < 2; i++) {
      uint4 v = p[i];
      u32 wsv[4] = {v.x, v.y, v.z, v.w};
#pragma unroll
      for (int j = 0; j < 4; j++)
#pragma unroll
        for (int kq = 0; kq < 4; kq++)
          bits |= ((((wsv[j] >> (kq * 8)) & 0xffu) != 0u) ? 1u : 0u) << (i * 16 + j * 4 + kq);
    }
  }
  mb[idx] = bits;
}

// ---- 128x128-tile bf16 GEMM, B^T layout ----
struct GArgs { const u16* X; const u16* W; const float* bias; void* out; int mode; float scale; };

__global__ __launch_bounds__(256, 2) void gemm_bt(GArgs g0, GArgs g1, GArgs g2) {
  GArgs ga = (blockIdx.z == 0) ? g0 : (blockIdx.z == 1 ? g1 : g2);
  const int K = 1024, N = 1024;
  __shared__ u16 As[128 * 32];
  __shared__ u16 Bs[128 * 32];
  const int t = threadIdx.x, w = t >> 6, l = t & 63;
  const int m0 = blockIdx.x * 128, n0 = blockIdx.y * 128;
  const int wm = (w >> 1) * 64, wn = (w & 1) * 64;
  const f32x4 fz = {0.f, 0.f, 0.f, 0.f};
  f32x4 acc[4][4];
#pragma unroll
  for (int i = 0; i < 4; i++)
#pragma unroll
    for (int j = 0; j < 4; j++) acc[i][j] = fz;

  for (int k0 = 0; k0 < K; k0 += 32) {
#pragma unroll
    for (int i = 0; i < 2; i++) {
      int idx = i * 256 + w * 64 + l;
      int r = idx >> 2, c = (idx & 3) * 8;
      __builtin_amdgcn_global_load_lds(
          reinterpret_cast<const unsigned*>(ga.X + (size_t)(m0 + r) * K + k0 + c),
          reinterpret_cast<unsigned*>(&As[(i * 256 + w * 64) * 8]), 16, 0, 0);
      __builtin_amdgcn_global_load_lds(
          reinterpret_cast<const unsigned*>(ga.W + (size_t)(n0 + r) * K + k0 + c),
          reinterpret_cast<unsigned*>(&Bs[(i * 256 + w * 64) * 8]), 16, 0, 0);
    }
    __syncthreads();
    bf16x8 af[4], bfr[4];
#pragma unroll
    for (int mt = 0; mt < 4; mt++)
      af[mt] = *reinterpret_cast<const bf16x8*>(&As[(wm + mt * 16 + (l & 15)) * 32 + (l >> 4) * 8]);
#pragma unroll
    for (int nt = 0; nt < 4; nt++)
      bfr[nt] = *reinterpret_cast<const bf16x8*>(&Bs[(wn + nt * 16 + (l & 15)) * 32 + (l >> 4) * 8]);
#pragma unroll
    for (int mt = 0; mt < 4; mt++)
#pragma unroll
      for (int nt = 0; nt < 4; nt++)
        acc[mt][nt] = MFMA_B16(af[mt], bfr[nt], acc[mt][nt]);
    __syncthreads();
  }

#pragma unroll
  for (int nt = 0; nt < 4; nt++) {
    int n = n0 + wn + nt * 16 + (l & 15);
    float bias = ga.bias[n];
#pragma unroll
    for (int mt = 0; mt < 4; mt++) {
      int mb = m0 + wm + mt * 16 + ((l >> 4) << 2);
#pragma unroll
      for (int r = 0; r < 4; r++) {
        int m = mb + r;
        float v = (acc[mt][nt][r] + bias) * ga.scale;
        if (ga.mode == 2) {
          reinterpret_cast<float*>(ga.out)[(size_t)m * N + n] = v;
        } else {
          int b = m >> 11, s = m & 2047, h = n >> 6, d = n & 63;
          if (ga.mode == 0)
            reinterpret_cast<u16*>(ga.out)[(((size_t)(b * NH + h) * NS + s) << 6) + d] = f2bf(v);
          else
            reinterpret_cast<u16*>(ga.out)[((size_t)(b * NH + h) * 64 + d) * NS + s] = f2bf(v);
        }
      }
    }
  }
}

// ---- attention: LDS-staged 2-phase pipeline with counted vmcnt (T3/T4 template).
// KVBLK=32. K tile [32 kc][64 d] XOR-swz (slot^=(kc&7)); V tile [64 dv][32 kc] XOR-swz
// (slot^=((dv>>1)&3)); both pre-swizzled at the GLOBAL source (rule #21).
// Pass 1: rowsum. Pass 2: normalized P -> Pf (full-line stores) + Ps -> PV. ----
__global__ __launch_bounds__(256, 4) void attn_kernel(
    const u16* __restrict__ qh, const u16* __restrict__ kh, const u16* __restrict__ vT,
    const u32* __restrict__ mb, float* __restrict__ attn, u16* __restrict__ ctx) {
  __shared__ u16 Ks[2][32 * 64];
  __shared__ u16 Vs[2][64 * 32];
  __shared__ u16 Ps[4][16 * 40];
  __shared__ float Pf[4][16 * 36];
  const int tid = threadIdx.x, w = tid >> 6, l = tid & 63;
  int id = blockIdx.x;
  int wgid = (id & 7) * 128 + (id >> 3);   // XCD-chunked bijective swizzle (1024 % 8 == 0)
  int qt = wgid & 31, pr = wgid >> 5;
  int h = pr & 15, b = pr >> 4;
  const size_t head = (size_t)b * NH + h;
  const u16* qp = qh + head * NS * 64;
  const u16* kp = kh + head * NS * 64;
  const u16* vp = vT + head * 64 * NS;
  const int qr0 = qt * 64 + w * 16;
  const int lo = l & 15, hi = l >> 4;
  const int rbase = hi << 2;
  const f32x4 fz = {0.f, 0.f, 0.f, 0.f};

  bf16x8 aq0, aq1;
  {
    const u16* p = qp + (size_t)(qr0 + lo) * 64 + hi * 8;
    aq0 = *reinterpret_cast<const bf16x8*>(p);
    aq1 = *reinterpret_cast<const bf16x8*>(p + 32);
  }
  const u32* mrow = mb + ((size_t)b * NS + qr0 + rbase) * 64;

  // staging sources, pre-swizzled (involution: same XOR applied on read)
  const int k_row = tid >> 3, k_slot = tid & 7;
  const u16* ksrc0 = kp + (size_t)k_row * 64 + ((k_slot ^ (k_row & 7)) * 8);
  const int v_dv = tid >> 2, v_slot = tid & 3;
  const u16* vsrc0 = vp + (size_t)v_dv * NS + ((v_slot ^ ((v_dv >> 1) & 3)) * 8);

  const int sxk = lo & 7;               // K read swizzle
  const int sxv = (lo >> 1) & 3;        // V read swizzle

  float rs0 = 0.f, rs1 = 0.f, rs2 = 0.f, rs3 = 0.f;

  // ================= pass 1: row sums =================
  __builtin_amdgcn_global_load_lds(reinterpret_cast<const unsigned*>(ksrc0),
                                   reinterpret_cast<unsigned*>(&Ks[0][w * 512]), 16, 0, 0);
  asm volatile("s_waitcnt vmcnt(0)" ::: "memory");
  __builtin_amdgcn_s_barrier();
  asm volatile("" ::: "memory");

  for (int t = 0; t < 64; ++t) {
    const u16* kbase = &Ks[t & 1][0];
    u16* kdst = &Ks[(t + 1) & 1][w * 512];
    __builtin_amdgcn_global_load_lds(
        reinterpret_cast<const unsigned*>(ksrc0 + (size_t)(t + 1) * 2048),
        reinterpret_cast<unsigned*>(kdst), 16, 0, 0);
    asm volatile("" ::: "memory");
    u32 m0 = mrow[t], m1 = mrow[64 + t], m2 = mrow[128 + t], m3 = mrow[192 + t];
    bf16x8 b00 = *reinterpret_cast<const bf16x8*>(&kbase[(lo) * 64 + ((hi ^ sxk) * 8)]);
    bf16x8 b01 = *reinterpret_cast<const bf16x8*>(&kbase[(lo) * 64 + (((4 + hi) ^ sxk) * 8)]);
    bf16x8 b10 = *reinterpret_cast<const bf16x8*>(&kbase[(16 + lo) * 64 + ((hi ^ sxk) * 8)]);
    bf16x8 b11 = *reinterpret_cast<const bf16x8*>(&kbase[(16 + lo) * 64 + (((4 + hi) ^ sxk) * 8)]);
    f32x4 s0 = MFMA_B16(aq1, b01, MFMA_B16(aq0, b00, fz));
    f32x4 s1 = MFMA_B16(aq1, b11, MFMA_B16(aq0, b10, fz));
    rs0 += ((m0 >> lo) & 1u) ? 0.f : __expf(s0[0]);
    rs1 += ((m1 >> lo) & 1u) ? 0.f : __expf(s0[1]);
    rs2 += ((m2 >> lo) & 1u) ? 0.f : __expf(s0[2]);
    rs3 += ((m3 >> lo) & 1u) ? 0.f : __expf(s0[3]);
    int bit1 = 16 + lo;
    rs0 += ((m0 >> bit1) & 1u) ? 0.f : __expf(s1[0]);
    rs1 += ((m1 >> bit1) & 1u) ? 0.f : __expf(s1[1]);
    rs2 += ((m2 >> bit1) & 1u) ? 0.f : __expf(s1[2]);
    rs3 += ((m3 >> bit1) & 1u) ? 0.f : __expf(s1[3]);
    asm volatile("s_waitcnt vmcnt(4)" ::: "memory");   // drain stage(t+1); mask loads are the 4 younger
    __builtin_amdgcn_s_barrier();
    asm volatile("" ::: "memory");
  }

  {
    float v;
    v = rs0; v += __shfl_xor(v, 1); v += __shfl_xor(v, 2); v += __shfl_xor(v, 4); v += __shfl_xor(v, 8);
    rs0 = 1.f / fmaxf(v, 1e-30f);
    v = rs1; v += __shfl_xor(v, 1); v += __shfl_xor(v, 2); v += __shfl_xor(v, 4); v += __shfl_xor(v, 8);
    rs1 = 1.f / fmaxf(v, 1e-30f);
    v = rs2; v += __shfl_xor(v, 1); v += __shfl_xor(v, 2); v += __shfl_xor(v, 4); v += __shfl_xor(v, 8);
    rs2 = 1.f / fmaxf(v, 1e-30f);
    v = rs3; v += __shfl_xor(v, 1); v += __shfl_xor(v, 2); v += __shfl_xor(v, 4); v += __shfl_xor(v, 8);
    rs3 = 1.f / fmaxf(v, 1e-30f);
  }

  // ================= pass 2: P stores + PV =================
  f32x4 c0 = fz, c1 = fz, c2 = fz, c3 = fz;
  float* abase = attn + (head * NS + qr0) * NS;
  float* pfw = &Pf[w][0];
  u16* psw = &Ps[w][0];
  const int srow = l >> 2, schunk = l & 3;

  __builtin_amdgcn_global_load_lds(reinterpret_cast<const unsigned*>(ksrc0),
                                   reinterpret_cast<unsigned*>(&Ks[0][w * 512]), 16, 0, 0);
  __builtin_amdgcn_global_load_lds(reinterpret_cast<const unsigned*>(vsrc0),
                                   reinterpret_cast<unsigned*>(&Vs[0][w * 512]), 16, 0, 0);
  asm volatile("s_waitcnt vmcnt(0)" ::: "memory");
  __builtin_amdgcn_s_barrier();
  asm volatile("" ::: "memory");

  for (int t = 0; t < 64; ++t) {
    const u16* kbase = &Ks[t & 1][0];
    const u16* vbase = &Vs[t & 1][0];
    u16* kdst = &Ks[(t + 1) & 1][w * 512];
    u16* vdst = &Vs[(t + 1) & 1][w * 512];
    __builtin_amdgcn_global_load_lds(
        reinterpret_cast<const unsigned*>(ksrc0 + (size_t)(t + 1) * 2048),
        reinterpret_cast<unsigned*>(kdst), 16, 0, 0);
    __builtin_amdgcn_global_load_lds(
        reinterpret_cast<const unsigned*>(vsrc0 + (size_t)(t + 1) * 32),
        reinterpret_cast<unsigned*>(vdst), 16, 0, 0);
    asm volatile("" ::: "memory");
    u32 m0 = mrow[t], m1 = mrow[64 + t], m2 = mrow[128 + t], m3 = mrow[192 + t];
    bf16x8 b00 = *reinterpret_cast<const bf16x8*>(&kbase[(lo) * 64 + ((hi ^ sxk) * 8)]);
    bf16x8 b01 = *reinterpret_cast<const bf16x8*>(&kbase[(lo) * 64 + (((4 + hi) ^ sxk) * 8)]);
    bf16x8 b10 = *reinterpret_cast<const bf16x8*>(&kbase[(16 + lo) * 64 + ((hi ^ sxk) * 8)]);
    bf16x8 b11 = *reinterpret_cast<const bf16x8*>(&kbase[(16 + lo) * 64 + (((4 + hi) ^ sxk) * 8)]);
    f32x4 s0 = MFMA_B16(aq1, b01, MFMA_B16(aq0, b00, fz));
    f32x4 s1 = MFMA_B16(aq1, b11, MFMA_B16(aq0, b10, fz));
    float p;
    p = ((m0 >> lo) & 1u) ? 0.f : __expf(s0[0]) * rs0;
    pfw[(rbase + 0) * 36 + lo] = p; psw[(rbase + 0) * 40 + lo] = f2bf(p);
    p = ((m1 >> lo) & 1u) ? 0.f : __expf(s0[1]) * rs1;
    pfw[(rbase + 1) * 36 + lo] = p; psw[(rbase + 1) * 40 + lo] = f2bf(p);
    p = ((m2 >> lo) & 1u) ? 0.f : __expf(s0[2]) * rs2;
    pfw[(rbase + 2) * 36 + lo] = p; psw[(rbase + 2) * 40 + lo] = f2bf(p);
    p = ((m3 >> lo) & 1u) ? 0.f : __expf(s0[3]) * rs3;
    pfw[(rbase + 3) * 36 + lo] = p; psw[(rbase + 3) * 40 + lo] = f2bf(p);
    int bit1 = 16 + lo;
    p = ((m0 >> bit1) & 1u) ? 0.f : __expf(s1[0]) * rs0;
    pfw[(rbase + 0) * 36 + 16 + lo] = p; psw[(rbase + 0) * 40 + 16 + lo] = f2bf(p);
    p = ((m1 >> bit1) & 1u) ? 0.f : __expf(s1[1]) * rs1;
    pfw[(rbase + 1) * 36 + 16 + lo] = p; psw[(rbase + 1) * 40 + 16 + lo] = f2bf(p);
    p = ((m2 >> bit1) & 1u) ? 0.f : __expf(s1[2]) * rs2;
    pfw[(rbase + 2) * 36 + 16 + lo] = p; psw[(rbase + 2) * 40 + 16 + lo] = f2bf(p);
    p = ((m3 >> bit1) & 1u) ? 0.f : __expf(s1[3]) * rs3;
    pfw[(rbase + 3) * 36 + 16 + lo] = p; psw[(rbase + 3) * 40 + 16 + lo] = f2bf(p);
    // PV from LDS (swizzled V), P from Ps
    bf16x8 pa = *reinterpret_cast<const bf16x8*>(&psw[lo * 40 + hi * 8]);
    bf16x8 v0 = *reinterpret_cast<const bf16x8*>(&vbase[(lo) * 32 + ((hi ^ sxv) * 8)]);
    bf16x8 v1 = *reinterpret_cast<const bf16x8*>(&vbase[(16 + lo) * 32 + ((hi ^ sxv) * 8)]);
    bf16x8 v2 = *reinterpret_cast<const bf16x8*>(&vbase[(32 + lo) * 32 + ((hi ^ sxv) * 8)]);
    bf16x8 v3 = *reinterpret_cast<const bf16x8*>(&vbase[(48 + lo) * 32 + ((hi ^ sxv) * 8)]);
    c0 = MFMA_B16(pa, v0, c0);
    c1 = MFMA_B16(pa, v1, c1);
    c2 = MFMA_B16(pa, v2, c2);
    c3 = MFMA_B16(pa, v3, c3);
    // full-line (128B/row) attn stores from Pf
    f32x4 o0 = *reinterpret_cast<const f32x4*>(&pfw[srow * 36 + schunk * 4]);
    f32x4 o1 = *reinterpret_cast<const f32x4*>(&pfw[srow * 36 + (schunk + 4) * 4]);
    *reinterpret_cast<f32x4*>(abase + (size_t)srow * NS + t * 32 + schunk * 4) = o0;
    *reinterpret_cast<f32x4*>(abase + (size_t)srow * NS + t * 32 + (schunk + 4) * 4) = o1;
    asm volatile("s_waitcnt vmcnt(6)" ::: "memory");  // drain stages(t+1); mask4+stores2 younger
    __builtin_amdgcn_s_barrier();
    asm volatile("" ::: "memory");
  }

  // ctx epilogue (P was normalized, cacc is final)
#define CTXW(cv, ct)                                                                   \
  {                                                                                    \
    ctx[((size_t)b * NS + qr0 + rbase + 0) * 1024 + h * 64 + (ct)*16 + lo] = f2bf(cv[0]); \
    ctx[((size_t)b * NS + qr0 + rbase + 1) * 1024 + h * 64 + (ct)*16 + lo] = f2bf(cv[1]); \
    ctx[((size_t)b * NS + qr0 + rbase + 2) * 1024 + h * 64 + (ct)*16 + lo] = f2bf(cv[2]); \
    ctx[((size_t)b * NS + qr0 + rbase + 3) * 1024 + h * 64 + (ct)*16 + lo] = f2bf(cv[3]); \
  }
  CTXW(c0, 0) CTXW(c1, 1) CTXW(c2, 2) CTXW(c3, 3)
#undef CTXW
}

extern "C" void kernel_launch(void* const* d_in, const int* in_sizes, int n_in,
                              void* d_out, int out_size, void* d_ws, size_t ws_size,
                              hipStream_t stream) {
  const float* Q = (const float*)d_in[0];
  const float* K = (const float*)d_in[1];
  const float* V = (const float*)d_in[2];
  const u32* mask = (const u32*)d_in[3];
  const float* wq = (const float*)d_in[4];
  const float* bq = (const float*)d_in[5];
  const float* wk = (const float*)d_in[6];
  const float* bk = (const float*)d_in[7];
  const float* wv = (const float*)d_in[8];
  const float* bv = (const float*)d_in[9];
  const float* wo = (const float*)d_in[10];
  const float* bo = (const float*)d_in[11];
  float* out = (float*)d_out;
  float* attn = out + (size_t)NB * NS * NDM;

  char* ws = (char*)d_ws;
  u16* Qb  = (u16*)(ws + 0);
  u16* Kb  = (u16*)(ws + 8388608);
  u16* Vb  = (u16*)(ws + 16777216);
  u16* wqT = (u16*)(ws + 25165824);
  u16* wkT = (u16*)(ws + 27262976);
  u16* wvT = (u16*)(ws + 29360128);
  u16* woT = (u16*)(ws + 31457280);
  u16* qhd = (u16*)(ws + 33554432);
  u16* khd = (u16*)(ws + 41943040);
  u16* vTd = (u16*)(ws + 50331648);
  u16* ctx = (u16*)(ws + 58720256);
  u32* mbits = (u32*)(ws + 0);

  cast_bf16<<<4096, 256, 0, stream>>>(Q, Qb, 1048576);
  cast_bf16<<<4096, 256, 0, stream>>>(K, Kb, 1048576);
  cast_bf16<<<4096, 256, 0, stream>>>(V, Vb, 1048576);
  transpose_w<<<dim3(32, 32), 256, 0, stream>>>(wq, wqT);
  transpose_w<<<dim3(32, 32), 256, 0, stream>>>(wk, wkT);
  transpose_w<<<dim3(32, 32), 256, 0, stream>>>(wv, wvT);
  transpose_w<<<dim3(32, 32), 256, 0, stream>>>(wo, woT);

  GArgs gq = {Qb, wqT, bq, (void*)qhd, 0, 0.125f};   // fold 1/sqrt(dk) into q
  GArgs gk = {Kb, wkT, bk, (void*)khd, 0, 1.0f};
  GArgs gv = {Vb, wvT, bv, (void*)vTd, 1, 1.0f};
  gemm_bt<<<dim3(32, 8, 3), 256, 0, stream>>>(gq, gk, gv);

  mask2bits<<<1024, 256, 0, stream>>>(mask, mbits);

  attn_kernel<<<1024, 256, 0, stream>>>(qhd, khd, vTd, mbits, attn, ctx);

  GArgs go = {ctx, woT, bo, d_out, 2, 1.0f};
  gemm_bt<<<dim3(32, 8, 1), 256, 0, stream>>>(go, go, go);
}